// Round 16
// baseline (3774.625 us; speedup 1.0000x reference)
//
#include <hip/hip_runtime.h>
#include <math.h>

// Forbid fma contraction for every expression in this file (np-matching arithmetic).
#pragma clang fp contract(off)

#define NB 8
#define NP 8192
#define NS 2048
#define NK 32
#define NWORK 992            // workers (grid 1024 = 8 fps + 24 spacers + 992)
#define TAGX 0x5A5A0000u     // tag XOR: defends handshake against ws poison patterns

// Decision-critical f32 ops as raw VALU instructions — cannot be contracted.
__device__ __forceinline__ float fsub(float a, float b) {
  float r; asm("v_sub_f32 %0, %1, %2" : "=v"(r) : "v"(a), "v"(b)); return r;
}
__device__ __forceinline__ float fmul(float a, float b) {
  float r; asm("v_mul_f32 %0, %1, %2" : "=v"(r) : "v"(a), "v"(b)); return r;
}
__device__ __forceinline__ float fadd(float a, float b) {
  float r; asm("v_add_f32 %0, %1, %2" : "=v"(r) : "v"(a), "v"(b)); return r;
}

// ---------------- FUSED persistent producer-consumer kernel ----------------
// R12-R15 post-mortem: three producer-side fixes (coord-carry, batched
// publish, spacers) failed to recover the ~400us "fps fused overhead" =>
// the system is plausibly CONSUMPTION-limited: 504 workers x (1 item / 78us
// occupied) ~ 6.5 items/us < 7.1-8.6 items/us production. Device VALUBusy
// 21.7% (idle issue slots), R13's fps slowdown showed through 1:1, R14/R15
// null — all consistent. R16: DOUBLE WORKER OCCUPANCY. launch_bounds(256,4),
// grid 1024: LDS 4x38.4KB=153.6<=160KB, VGPR 4 waves/SIMD x112=448<=512 =>
// 4 blocks/CU, all resident. Deadlock-safe regardless of residency: tags
// persist in memory (late workers read already-set tags); workers never wait
// on each other; fps (blocks 0..7, dispatched first) waits on nobody.
// Spacers (within<8, layer>=1) vacate fps-CU co-tenant slots on all layers.
//
// fps semantics (R8-verified, bit-identical): unfused f32 distances
// ((dx*dx+dy*dy)+dz*dz, contract(off)); u64 (key<<32 | ~idx) max == (max key,
// lowest index) == np.argmax first-occurrence. Thread t owns points
// j*1024+4t+k; ascending (j,k) => ascending global idx. Register residency
// via volatile LDS loads (planes staged one-at-a-time through smem).
__global__ __launch_bounds__(256, 4) void fused_kernel(
    const float* __restrict__ xyz, const float* __restrict__ points,
    const float* __restrict__ w0, const float* __restrict__ b0, const float* __restrict__ g0,
    const float* __restrict__ bt0, const float* __restrict__ m0, const float* __restrict__ v0,
    const float* __restrict__ w1, const float* __restrict__ b1, const float* __restrict__ g1,
    const float* __restrict__ bt1, const float* __restrict__ m1, const float* __restrict__ v1,
    const float* __restrict__ w2, const float* __restrict__ b2, const float* __restrict__ g2,
    const float* __restrict__ bt2, const float* __restrict__ m2, const float* __restrict__ v2,
    float* __restrict__ new_xyz, float* __restrict__ out_pts,
    unsigned long long* __restrict__ hs) {
  __shared__ __align__(16) float smem[9552];
  __shared__ unsigned long long wbest[2][4];
  __shared__ float cxyz[3];

  const int tid = threadIdx.x;
  const int lane = tid & 63, wv = tid >> 6;
  const int bid = (int)blockIdx.x;
  const int layer = bid >> 8, within = bid & 255;

  if (within < NB && layer > 0) return;   // spacer: vacate fps-CU co-tenant slot

  if (bid < NB) {
    // ================= FPS producer (one block per batch) =================
    __builtin_amdgcn_s_setprio(1);     // protect fps issue from any co-tenant
    const int b = bid;
    const float* xb = xyz + (size_t)b * NP * 3;
    const int tb = tid << 2;
    float* cq = smem + 9000;           // 8-slot centroid queue (24 floats), dead area
    float rx[32], ry[32], rz[32];
    // stage each SoA plane through smem, then volatile-LDS load to registers
    // (volatile = cannot be rematerialized/sunk into the loop; R7-verified)
    for (int i = 0; i < 32; i++) { int p = tid * 32 + i; smem[p] = xb[p * 3 + 0]; }
    __syncthreads();
#pragma unroll
    for (int j = 0; j < 8; j++)
#pragma unroll
      for (int k = 0; k < 4; k++)
        rx[j * 4 + k] = *(volatile const float*)&smem[j * 1024 + tb + k];
    __syncthreads();
    for (int i = 0; i < 32; i++) { int p = tid * 32 + i; smem[p] = xb[p * 3 + 1]; }
    __syncthreads();
#pragma unroll
    for (int j = 0; j < 8; j++)
#pragma unroll
      for (int k = 0; k < 4; k++)
        ry[j * 4 + k] = *(volatile const float*)&smem[j * 1024 + tb + k];
    __syncthreads();
    for (int i = 0; i < 32; i++) { int p = tid * 32 + i; smem[p] = xb[p * 3 + 2]; }
    __syncthreads();
#pragma unroll
    for (int j = 0; j < 8; j++)
#pragma unroll
      for (int k = 0; k < 4; k++)
        rz[j * 4 + k] = *(volatile const float*)&smem[j * 1024 + tb + k];
    __syncthreads();

    float dist[32];
#pragma unroll
    for (int i = 0; i < 32; i++) dist[i] = 1e10f;

    float fx = xb[0], fy = xb[1], fz = xb[2];   // farthest = index 0 at t=0
    for (int t = 0; t < NS; t++) {
      if (tid == 0) {
        // stage centroid t into the LDS queue (cheap ds_write; drains fast)
        const int sl = (t & 7) * 3;
        cq[sl + 0] = fx; cq[sl + 1] = fy; cq[sl + 2] = fz;
        if ((t & 7) == 7) {
          // flush 8 centroids: 24 stores + 24 tagged device-scope atomics
          const int t0 = t - 7;
#pragma unroll
          for (int q = 0; q < 8; q++) {
            const int s = t0 + q;
            float qx = cq[q * 3 + 0], qy = cq[q * 3 + 1], qz = cq[q * 3 + 2];
            float* o = new_xyz + ((size_t)b * NS + s) * 3;
            o[0] = qx; o[1] = qy; o[2] = qz;
            unsigned long long tg =
                (unsigned long long)(((unsigned)(s + 1)) ^ TAGX) << 32;
            unsigned long long* h = hs + ((size_t)b * NS + s) * 3;
            atomicExch(&h[0], tg | (unsigned long long)__float_as_uint(qx));
            atomicExch(&h[1], tg | (unsigned long long)__float_as_uint(qy));
            atomicExch(&h[2], tg | (unsigned long long)__float_as_uint(qz));
          }
        }
      }
      const int par = t & 1;
      float lmax = -1.0f; int li = 0;
#pragma unroll
      for (int i = 0; i < 32; i++) {
        float dx = rx[i] - fx;
        float dy = ry[i] - fy;
        float dz = rz[i] - fz;
        float d = dx * dx + dy * dy + dz * dz;  // contract(off): 3 mul + 2 add
        float nd = fminf(dist[i], d);
        dist[i] = nd;
        bool gt = nd > lmax;
        li = gt ? i : li;
        lmax = gt ? nd : lmax;
      }
      const unsigned gidx = (unsigned)(((li >> 2) << 10) | (tid << 2) | (li & 3));
      // ---- single packed-u64 DPP wave reduce (VALU pipe only) ----
      unsigned long long m = ((unsigned long long)__float_as_uint(lmax) << 32)
                           | (unsigned long long)(~gidx);
#define DPP_MAX64(ctrl) { \
      unsigned _lo = (unsigned)__builtin_amdgcn_update_dpp(0, (int)(unsigned)m, (ctrl), 0xf, 0xf, false); \
      unsigned _hi = (unsigned)__builtin_amdgcn_update_dpp(0, (int)(unsigned)(m >> 32), (ctrl), 0xf, 0xf, false); \
      unsigned long long _o = ((unsigned long long)_hi << 32) | _lo; \
      if (_o > m) m = _o; }
      DPP_MAX64(0x111) DPP_MAX64(0x112) DPP_MAX64(0x114) DPP_MAX64(0x118)
      DPP_MAX64(0x142) DPP_MAX64(0x143)
#undef DPP_MAX64
      if (lane == 63) wbest[par][wv] = m;
      __syncthreads();                          // single barrier per iteration
      unsigned long long mm = wbest[par][0];
#pragma unroll
      for (int w = 1; w < 4; w++) { unsigned long long c = wbest[par][w]; if (c > mm) mm = c; }
      int bp = (int)(~(unsigned)(mm & 0xFFFFFFFFull));
      // winner coords from global (L2-hot; identical bits to the staged copy)
      fx = xb[bp * 3 + 0]; fy = xb[bp * 3 + 1]; fz = xb[bp * 3 + 2];
      // parity double-buffer: next iteration writes wbest[1-par] — no WAR race
    }
    return;
  }

  // ================= ball+mlp worker (persistent, s-major items) =================
  const int wid = layer * 248 + (within - NB);   // 0..991
  // ball-phase layout
  float* sd         = smem;                      // 8192 keys
  int* hist4        = (int*)(smem + 8192);       // 4 waves x 256 buckets
  int* cnts         = (int*)(smem + 9216);       // 2
  unsigned* sprefix = (unsigned*)(smem + 9218);
  int* sbelow       = (int*)(smem + 9219);
  int* snear_s      = (int*)(smem + 9220);
  int* wsum         = (int*)(smem + 9224);       // 4
  int* selA         = (int*)(smem + 9232);       // 32
  int* tib          = (int*)(smem + 9264);       // 256 (reused as qsl)
  int* myhist = hist4 + wv * 256;
  const unsigned long long lmask_lt = (lane == 0) ? 0ull : (~0ull >> (64 - lane));

  for (int jit = wid; jit < NB * NS; jit += NWORK) {
    const int s = jit >> 3, b = jit & 7;
    const int cs = b * NS + s;
    const float* xb = xyz + (size_t)b * NP * 3;
    // ---- wait for centroid (b,s): poll tagged words ----
    if (tid == 0) {
      const unsigned want = ((unsigned)(s + 1)) ^ TAGX;
      unsigned long long* h = hs + ((size_t)b * NS + s) * 3;
      unsigned long long v0, v1, v2;
      for (;;) { v0 = atomicAdd(&h[0], 0ull); if ((unsigned)(v0 >> 32) == want) break; __builtin_amdgcn_s_sleep(1); }
      for (;;) { v1 = atomicAdd(&h[1], 0ull); if ((unsigned)(v1 >> 32) == want) break; __builtin_amdgcn_s_sleep(1); }
      for (;;) { v2 = atomicAdd(&h[2], 0ull); if ((unsigned)(v2 >> 32) == want) break; __builtin_amdgcn_s_sleep(1); }
      cxyz[0] = __uint_as_float((unsigned)v0);
      cxyz[1] = __uint_as_float((unsigned)v1);
      cxyz[2] = __uint_as_float((unsigned)v2);
    }
    __syncthreads();
    const float cx = cxyz[0], cy = cxyz[1], cz = cxyz[2];
    const float Sc = fadd(fadd(fmul(cx, cx), fmul(cy, cy)), fmul(cz, cz));
    for (int i = lane; i < 256; i += 64) myhist[i] = 0;
    for (int j = 0; j < 32; j++) {
      int p = j * 256 + tid;
      float x = xb[p * 3 + 0], y = xb[p * 3 + 1], z = xb[p * 3 + 2];
      float Sn    = fadd(fadd(fmul(x, x), fmul(y, y)), fmul(z, z));
      float inner = fmaf(cz, z, fmaf(cy, y, fmul(cx, x)));
      float d2    = fsub(fadd(Sc, Sn), fmul(2.0f, inner));
      float kk = __fsqrt_rn(fmaxf(d2, 0.0f));
      sd[p] = kk;
      // ballot-combined histogram (R9): one atomic per distinct bucket
      unsigned bucket = __float_as_uint(kk) >> 24;
      unsigned long long rem = __ballot(1);
      while (rem) {
        int leader = (int)__ffsll((unsigned long long)rem) - 1;
        unsigned lb = (unsigned)__shfl((int)bucket, leader);
        unsigned long long mk = __ballot(bucket == lb);
        if (lane == leader) atomicAdd(&myhist[lb], (int)__popcll(mk));
        rem &= ~mk;
      }
    }
    unsigned prefix = 0; int below = 0;
    for (int round = 0; round < 4; round++) {
      const int shift = 24 - 8 * round;
      if (round > 0) {
        for (int i = lane; i < 256; i += 64) myhist[i] = 0;
        __syncthreads();
        for (int j = 0; j < 32; j++) {
          unsigned kb = __float_as_uint(sd[j * 256 + tid]);
          if ((kb >> (shift + 8)) == (prefix >> (shift + 8)))
            atomicAdd(&myhist[(kb >> shift) & 255], 1);
        }
      }
      __syncthreads();
      int h = hist4[tid] + hist4[256 + tid] + hist4[512 + tid] + hist4[768 + tid];
      int v = h;
#pragma unroll
      for (int off = 1; off < 64; off <<= 1) {
        int u = __shfl_up(v, off);
        if (lane >= off) v += u;
      }
      if (lane == 63) wsum[wv] = v;
      __syncthreads();
      int base = below;
      for (int w = 0; w < wv; w++) base += wsum[w];
      int excl = base + v - h;
      if (excl < NK && excl + h >= NK) {    // unique crossing thread
        *sprefix = prefix | ((unsigned)tid << shift);
        *sbelow = excl;
      }
      __syncthreads();
      prefix = *sprefix; below = *sbelow;
    }
    const unsigned K32 = prefix;
    if (tid < 2) cnts[tid] = 0;
    __syncthreads();
    for (int j = 0; j < 32; j++) {
      int p = j * 256 + tid;
      unsigned kb = __float_as_uint(sd[p]);
      bool isA = (kb < K32);
      bool isT = (kb == K32);
      unsigned long long mA = __ballot(isA);
      if (isA) {
        int leader = (int)__ffsll(mA) - 1;
        int basev = 0;
        if (lane == leader) basev = atomicAdd(&cnts[0], (int)__popcll(mA));
        basev = __shfl(basev, leader);
        int q = basev + (int)__popcll(mA & lmask_lt);
        if (q < NK) selA[q] = p;
      }
      unsigned long long mT = __ballot(isT);
      if (isT) {
        int leader = (int)__ffsll(mT) - 1;
        int basev = 0;
        if (lane == leader) basev = atomicAdd(&cnts[1], (int)__popcll(mT));
        basev = __shfl(basev, leader);
        int q = basev + (int)__popcll(mT & lmask_lt);
        if (q < 256) tib[q] = p;
      }
    }
    __syncthreads();
    const int n1 = cnts[0] < NK ? cnts[0] : NK;
    int nt = cnts[1]; if (nt > 256) nt = 256;
    if (tid == 0) {
      int need = NK - n1;
      for (int a = 0; a < need; a++) {       // ties -> lowest indices (top_k stable)
        int bj = -1; int bidx = 0x7fffffff;
        for (int j = 0; j < nt; j++) {
          int p = tib[j];
          if (p >= 0 && p < bidx) { bidx = p; bj = j; }
        }
        if (bj >= 0) { selA[n1 + a] = bidx; tib[bj] = -1; }
        else selA[n1 + a] = selA[0];
      }
      float bk = 1e30f; int bp = 0x7fffffff;  // nearest = (min key, min idx)
      for (int j = 0; j < NK; j++) {
        int p = selA[j]; float kk = sd[p];
        if (kk < bk || (kk == bk && p < bp)) { bk = kk; bp = p; }
      }
      *snear_s = bp;
    }
    __syncthreads();
    // transition: final indices into dead tib region
    int* qsl = tib;
    if (tid < NK) {
      int p = selA[tid];
      qsl[tid] = (sd[p] > 0.25f) ? *snear_s : p;
    }
    __syncthreads();                       // sd/selA dead beyond this point

    // ---- mlp phase (layout inside dead sd region) ----
    float* x1   = smem;             // 32*64
    float* x2   = smem + 2048;      // 32*64
    float* pmax = smem + 4096;      // 8*128
    float* gin  = smem + 5120;      // 32*12

    for (int e = tid; e < 288; e += 256) {
      int k = e / 9, c = e % 9;
      int p = qsl[k];
      float v;
      if (c < 3) {
        float cc = (c == 0) ? cx : (c == 1 ? cy : cz);
        v = fsub(xyz[((size_t)b * NP + p) * 3 + c], cc);
      } else {
        v = points[((size_t)b * NP + p) * 6 + (c - 3)];
      }
      gin[k * 12 + c] = v;
    }
    __syncthreads();
    { // L1
      int o = tid & 63, k0 = (tid >> 6) * 8;
      float wr[9];
#pragma unroll
      for (int c = 0; c < 9; c++) wr[c] = w0[o * 9 + c];
      float bb = b0[o], bm = m0[o], bg = g0[o], bbt = bt0[o];
      float br = 1.0f / __fsqrt_rn(fadd(v0[o], 1e-5f));
#pragma unroll
      for (int j = 0; j < 8; j++) {
        int k = k0 + j;
        const float4* gq = (const float4*)&gin[k * 12];
        float4 q0 = gq[0], q1 = gq[1], q2 = gq[2];
        float acc = 0.f;
        acc = fmaf(wr[0], q0.x, acc); acc = fmaf(wr[1], q0.y, acc);
        acc = fmaf(wr[2], q0.z, acc); acc = fmaf(wr[3], q0.w, acc);
        acc = fmaf(wr[4], q1.x, acc); acc = fmaf(wr[5], q1.y, acc);
        acc = fmaf(wr[6], q1.z, acc); acc = fmaf(wr[7], q1.w, acc);
        acc = fmaf(wr[8], q2.x, acc);
        float y = fadd(acc, bb);
        y = fadd(fmul(fmul(bg, fsub(y, bm)), br), bbt);
        x1[k * 64 + o] = fmaxf(y, 0.f);
      }
    }
    __syncthreads();
    { // L2
      int o0 = (tid & 31) * 2, k0 = (tid >> 5) * 4;
      float acc[2][4];
#pragma unroll
      for (int oo = 0; oo < 2; oo++)
#pragma unroll
        for (int kk = 0; kk < 4; kk++) acc[oo][kk] = 0.f;
#pragma unroll
      for (int c4 = 0; c4 < 16; c4++) {
        float4 xq[4];
#pragma unroll
        for (int kk = 0; kk < 4; kk++) xq[kk] = *(const float4*)&x1[(k0 + kk) * 64 + c4 * 4];
#pragma unroll
        for (int oo = 0; oo < 2; oo++) {
          float4 wq = *(const float4*)&w1[(o0 + oo) * 64 + c4 * 4];
#pragma unroll
          for (int kk = 0; kk < 4; kk++) {
            acc[oo][kk] = fmaf(wq.x, xq[kk].x, acc[oo][kk]);
            acc[oo][kk] = fmaf(wq.y, xq[kk].y, acc[oo][kk]);
            acc[oo][kk] = fmaf(wq.z, xq[kk].z, acc[oo][kk]);
            acc[oo][kk] = fmaf(wq.w, xq[kk].w, acc[oo][kk]);
          }
        }
      }
#pragma unroll
      for (int oo = 0; oo < 2; oo++) {
        int o = o0 + oo;
        float bb = b1[o], bm = m1[o], bg = g1[o], bbt = bt1[o];
        float br = 1.0f / __fsqrt_rn(fadd(v1[o], 1e-5f));
#pragma unroll
        for (int kk = 0; kk < 4; kk++) {
          float y = fadd(acc[oo][kk], bb);
          y = fadd(fmul(fmul(bg, fsub(y, bm)), br), bbt);
          x2[(k0 + kk) * 64 + o] = fmaxf(y, 0.f);
        }
      }
    }
    __syncthreads();
    { // L3 + per-k-group max
      int ch0 = (tid & 31) * 4, k0 = (tid >> 5) * 4, kg = tid >> 5;
      float acc[4][4];
#pragma unroll
      for (int cc = 0; cc < 4; cc++)
#pragma unroll
        for (int kk = 0; kk < 4; kk++) acc[cc][kk] = 0.f;
#pragma unroll
      for (int c4 = 0; c4 < 16; c4++) {
        float4 xq[4];
#pragma unroll
        for (int kk = 0; kk < 4; kk++) xq[kk] = *(const float4*)&x2[(k0 + kk) * 64 + c4 * 4];
#pragma unroll
        for (int cc = 0; cc < 4; cc++) {
          float4 wq = *(const float4*)&w2[(ch0 + cc) * 64 + c4 * 4];
#pragma unroll
          for (int kk = 0; kk < 4; kk++) {
            acc[cc][kk] = fmaf(wq.x, xq[kk].x, acc[cc][kk]);
            acc[cc][kk] = fmaf(wq.y, xq[kk].y, acc[cc][kk]);
            acc[cc][kk] = fmaf(wq.z, xq[kk].z, acc[cc][kk]);
            acc[cc][kk] = fmaf(wq.w, xq[kk].w, acc[cc][kk]);
          }
        }
      }
#pragma unroll
      for (int cc = 0; cc < 4; cc++) {
        int ch = ch0 + cc;
        float bb = b2[ch], bm = m2[ch], bg = g2[ch], bbt = bt2[ch];
        float br = 1.0f / __fsqrt_rn(fadd(v2[ch], 1e-5f));
        float mx = -1e30f;
#pragma unroll
        for (int kk = 0; kk < 4; kk++) {
          float y = fadd(acc[cc][kk], bb);
          y = fadd(fmul(fmul(bg, fsub(y, bm)), br), bbt);
          mx = fmaxf(mx, fmaxf(y, 0.f));
        }
        pmax[kg * 128 + ch] = mx;
      }
    }
    __syncthreads();
    if (tid < 128) {
      float m = pmax[tid];
#pragma unroll
      for (int g = 1; g < 8; g++) m = fmaxf(m, pmax[g * 128 + tid]);
      out_pts[(size_t)cs * 128 + tid] = m;
    }
    __syncthreads();                       // before smem reuse by next item
  }
}

extern "C" void kernel_launch(void* const* d_in, const int* in_sizes, int n_in,
                              void* d_out, int out_size, void* d_ws, size_t ws_size,
                              hipStream_t stream) {
  (void)in_sizes; (void)n_in; (void)out_size; (void)ws_size;
  const float* xyz    = (const float*)d_in[0];
  const float* points = (const float*)d_in[1];
  const float* w0 = (const float*)d_in[2];
  const float* b0 = (const float*)d_in[3];
  const float* g0 = (const float*)d_in[4];
  const float* bt0 = (const float*)d_in[5];
  const float* m0 = (const float*)d_in[6];
  const float* v0 = (const float*)d_in[7];
  const float* w1 = (const float*)d_in[8];
  const float* b1 = (const float*)d_in[9];
  const float* g1 = (const float*)d_in[10];
  const float* bt1 = (const float*)d_in[11];
  const float* m1 = (const float*)d_in[12];
  const float* v1 = (const float*)d_in[13];
  const float* w2 = (const float*)d_in[14];
  const float* b2 = (const float*)d_in[15];
  const float* g2 = (const float*)d_in[16];
  const float* bt2 = (const float*)d_in[17];
  const float* m2 = (const float*)d_in[18];
  const float* v2 = (const float*)d_in[19];

  float* new_xyz = (float*)d_out;                         // 8*2048*3 f32
  float* out_pts = (float*)d_out + (size_t)NB * NS * 3;   // 8*2048*128 f32
  unsigned long long* hs = (unsigned long long*)d_ws;     // 8*2048*3 u64 = 384 KiB

  fused_kernel<<<1024, 256, 0, stream>>>(xyz, points,
                                         w0, b0, g0, bt0, m0, v0,
                                         w1, b1, g1, bt1, m1, v1,
                                         w2, b2, g2, bt2, m2, v2,
                                         new_xyz, out_pts, hs);
}

// Round 17
// 3070.085 us; speedup vs baseline: 1.2295x; 1.2295x over previous
//
#include <hip/hip_runtime.h>
#include <math.h>

// Forbid fma contraction for every expression in this file (np-matching arithmetic).
#pragma clang fp contract(off)

#define NB 8
#define NP 8192
#define NS 2048
#define NK 32
#define NWORK 992            // workers (grid 1024 = 8 fps + 24 spacers + 992)
#define TAGX 0x5A5A0000u     // tag XOR: defends handshake against ws poison patterns

// Decision-critical f32 ops as raw VALU instructions — cannot be contracted.
__device__ __forceinline__ float fsub(float a, float b) {
  float r; asm("v_sub_f32 %0, %1, %2" : "=v"(r) : "v"(a), "v"(b)); return r;
}
__device__ __forceinline__ float fmul(float a, float b) {
  float r; asm("v_mul_f32 %0, %1, %2" : "=v"(r) : "v"(a), "v"(b)); return r;
}
__device__ __forceinline__ float fadd(float a, float b) {
  float r; asm("v_add_f32 %0, %1, %2" : "=v"(r) : "v"(a), "v"(b)); return r;
}

// ---------------- FUSED persistent producer-consumer kernel ----------------
// R16 post-mortem: launch_bounds(256,4) capped VGPR at 64 -> fps point set
// SPILLED to scratch (FETCH 3.0K->13.5K KB, dur +1.4ms) — the bound applies
// kernel-wide, killing the R7 volatile-residency mechanism. BUT it proved the
// occupancy lever: grid 1024 doubled residency to 4 blocks/CU (Occ 23->46%).
// R12-15's 2 blocks/CU was GRID-limited (520/256), not bounds-limited.
// R17: decouple — launch_bounds(256,2) (VGPR budget 256 -> allocator's ~112,
// no spill; R12-15-verified) + grid 1024. HW residency comes from actual
// resources: 4 waves/SIMD x 112 = 448 <= 512 VGPR, 4 x 38.4 = 153.6 <= 160KB
// LDS => 4 blocks/CU with full registers. Deadlock-safe in all residency
// scenarios: fps (blocks 0..7, dispatched first) waits on nobody; workers
// wait only on fps tags which persist in memory; non-resident workers queue
// behind finishing residents (residents always finish: fps always runs).
//
// fps semantics (R8-verified, bit-identical): unfused f32 distances
// ((dx*dx+dy*dy)+dz*dz, contract(off)); u64 (key<<32 | ~idx) max == (max key,
// lowest index) == np.argmax first-occurrence. Thread t owns points
// j*1024+4t+k; ascending (j,k) => ascending global idx. Register residency
// via volatile LDS loads (planes staged one-at-a-time through smem).
__global__ __launch_bounds__(256, 2) void fused_kernel(
    const float* __restrict__ xyz, const float* __restrict__ points,
    const float* __restrict__ w0, const float* __restrict__ b0, const float* __restrict__ g0,
    const float* __restrict__ bt0, const float* __restrict__ m0, const float* __restrict__ v0,
    const float* __restrict__ w1, const float* __restrict__ b1, const float* __restrict__ g1,
    const float* __restrict__ bt1, const float* __restrict__ m1, const float* __restrict__ v1,
    const float* __restrict__ w2, const float* __restrict__ b2, const float* __restrict__ g2,
    const float* __restrict__ bt2, const float* __restrict__ m2, const float* __restrict__ v2,
    float* __restrict__ new_xyz, float* __restrict__ out_pts,
    unsigned long long* __restrict__ hs) {
  __shared__ __align__(16) float smem[9552];
  __shared__ unsigned long long wbest[2][4];
  __shared__ float cxyz[3];

  const int tid = threadIdx.x;
  const int lane = tid & 63, wv = tid >> 6;
  const int bid = (int)blockIdx.x;
  const int layer = bid >> 8, within = bid & 255;

  if (within < NB && layer > 0) return;   // spacer: vacate fps-CU co-tenant slot

  if (bid < NB) {
    // ================= FPS producer (one block per batch) =================
    __builtin_amdgcn_s_setprio(1);     // protect fps issue from any co-tenant
    const int b = bid;
    const float* xb = xyz + (size_t)b * NP * 3;
    const int tb = tid << 2;
    float* cq = smem + 9000;           // 8-slot centroid queue (24 floats), dead area
    float rx[32], ry[32], rz[32];
    // stage each SoA plane through smem, then volatile-LDS load to registers
    // (volatile = cannot be rematerialized/sunk into the loop; R7-verified)
    for (int i = 0; i < 32; i++) { int p = tid * 32 + i; smem[p] = xb[p * 3 + 0]; }
    __syncthreads();
#pragma unroll
    for (int j = 0; j < 8; j++)
#pragma unroll
      for (int k = 0; k < 4; k++)
        rx[j * 4 + k] = *(volatile const float*)&smem[j * 1024 + tb + k];
    __syncthreads();
    for (int i = 0; i < 32; i++) { int p = tid * 32 + i; smem[p] = xb[p * 3 + 1]; }
    __syncthreads();
#pragma unroll
    for (int j = 0; j < 8; j++)
#pragma unroll
      for (int k = 0; k < 4; k++)
        ry[j * 4 + k] = *(volatile const float*)&smem[j * 1024 + tb + k];
    __syncthreads();
    for (int i = 0; i < 32; i++) { int p = tid * 32 + i; smem[p] = xb[p * 3 + 2]; }
    __syncthreads();
#pragma unroll
    for (int j = 0; j < 8; j++)
#pragma unroll
      for (int k = 0; k < 4; k++)
        rz[j * 4 + k] = *(volatile const float*)&smem[j * 1024 + tb + k];
    __syncthreads();

    float dist[32];
#pragma unroll
    for (int i = 0; i < 32; i++) dist[i] = 1e10f;

    float fx = xb[0], fy = xb[1], fz = xb[2];   // farthest = index 0 at t=0
    for (int t = 0; t < NS; t++) {
      if (tid == 0) {
        // stage centroid t into the LDS queue (cheap ds_write; drains fast)
        const int sl = (t & 7) * 3;
        cq[sl + 0] = fx; cq[sl + 1] = fy; cq[sl + 2] = fz;
        if ((t & 7) == 7) {
          // flush 8 centroids: 24 stores + 24 tagged device-scope atomics
          const int t0 = t - 7;
#pragma unroll
          for (int q = 0; q < 8; q++) {
            const int s = t0 + q;
            float qx = cq[q * 3 + 0], qy = cq[q * 3 + 1], qz = cq[q * 3 + 2];
            float* o = new_xyz + ((size_t)b * NS + s) * 3;
            o[0] = qx; o[1] = qy; o[2] = qz;
            unsigned long long tg =
                (unsigned long long)(((unsigned)(s + 1)) ^ TAGX) << 32;
            unsigned long long* h = hs + ((size_t)b * NS + s) * 3;
            atomicExch(&h[0], tg | (unsigned long long)__float_as_uint(qx));
            atomicExch(&h[1], tg | (unsigned long long)__float_as_uint(qy));
            atomicExch(&h[2], tg | (unsigned long long)__float_as_uint(qz));
          }
        }
      }
      const int par = t & 1;
      float lmax = -1.0f; int li = 0;
#pragma unroll
      for (int i = 0; i < 32; i++) {
        float dx = rx[i] - fx;
        float dy = ry[i] - fy;
        float dz = rz[i] - fz;
        float d = dx * dx + dy * dy + dz * dz;  // contract(off): 3 mul + 2 add
        float nd = fminf(dist[i], d);
        dist[i] = nd;
        bool gt = nd > lmax;
        li = gt ? i : li;
        lmax = gt ? nd : lmax;
      }
      const unsigned gidx = (unsigned)(((li >> 2) << 10) | (tid << 2) | (li & 3));
      // ---- single packed-u64 DPP wave reduce (VALU pipe only) ----
      unsigned long long m = ((unsigned long long)__float_as_uint(lmax) << 32)
                           | (unsigned long long)(~gidx);
#define DPP_MAX64(ctrl) { \
      unsigned _lo = (unsigned)__builtin_amdgcn_update_dpp(0, (int)(unsigned)m, (ctrl), 0xf, 0xf, false); \
      unsigned _hi = (unsigned)__builtin_amdgcn_update_dpp(0, (int)(unsigned)(m >> 32), (ctrl), 0xf, 0xf, false); \
      unsigned long long _o = ((unsigned long long)_hi << 32) | _lo; \
      if (_o > m) m = _o; }
      DPP_MAX64(0x111) DPP_MAX64(0x112) DPP_MAX64(0x114) DPP_MAX64(0x118)
      DPP_MAX64(0x142) DPP_MAX64(0x143)
#undef DPP_MAX64
      if (lane == 63) wbest[par][wv] = m;
      __syncthreads();                          // single barrier per iteration
      unsigned long long mm = wbest[par][0];
#pragma unroll
      for (int w = 1; w < 4; w++) { unsigned long long c = wbest[par][w]; if (c > mm) mm = c; }
      int bp = (int)(~(unsigned)(mm & 0xFFFFFFFFull));
      // winner coords from global (L2-hot; identical bits to the staged copy)
      fx = xb[bp * 3 + 0]; fy = xb[bp * 3 + 1]; fz = xb[bp * 3 + 2];
      // parity double-buffer: next iteration writes wbest[1-par] — no WAR race
    }
    return;
  }

  // ================= ball+mlp worker (persistent, s-major items) =================
  const int wid = layer * 248 + (within - NB);   // 0..991
  // ball-phase layout
  float* sd         = smem;                      // 8192 keys
  int* hist4        = (int*)(smem + 8192);       // 4 waves x 256 buckets
  int* cnts         = (int*)(smem + 9216);       // 2
  unsigned* sprefix = (unsigned*)(smem + 9218);
  int* sbelow       = (int*)(smem + 9219);
  int* snear_s      = (int*)(smem + 9220);
  int* wsum         = (int*)(smem + 9224);       // 4
  int* selA         = (int*)(smem + 9232);       // 32
  int* tib          = (int*)(smem + 9264);       // 256 (reused as qsl)
  int* myhist = hist4 + wv * 256;
  const unsigned long long lmask_lt = (lane == 0) ? 0ull : (~0ull >> (64 - lane));

  for (int jit = wid; jit < NB * NS; jit += NWORK) {
    const int s = jit >> 3, b = jit & 7;
    const int cs = b * NS + s;
    const float* xb = xyz + (size_t)b * NP * 3;
    // ---- wait for centroid (b,s): poll tagged words ----
    if (tid == 0) {
      const unsigned want = ((unsigned)(s + 1)) ^ TAGX;
      unsigned long long* h = hs + ((size_t)b * NS + s) * 3;
      unsigned long long v0, v1, v2;
      for (;;) { v0 = atomicAdd(&h[0], 0ull); if ((unsigned)(v0 >> 32) == want) break; __builtin_amdgcn_s_sleep(1); }
      for (;;) { v1 = atomicAdd(&h[1], 0ull); if ((unsigned)(v1 >> 32) == want) break; __builtin_amdgcn_s_sleep(1); }
      for (;;) { v2 = atomicAdd(&h[2], 0ull); if ((unsigned)(v2 >> 32) == want) break; __builtin_amdgcn_s_sleep(1); }
      cxyz[0] = __uint_as_float((unsigned)v0);
      cxyz[1] = __uint_as_float((unsigned)v1);
      cxyz[2] = __uint_as_float((unsigned)v2);
    }
    __syncthreads();
    const float cx = cxyz[0], cy = cxyz[1], cz = cxyz[2];
    const float Sc = fadd(fadd(fmul(cx, cx), fmul(cy, cy)), fmul(cz, cz));
    for (int i = lane; i < 256; i += 64) myhist[i] = 0;
    for (int j = 0; j < 32; j++) {
      int p = j * 256 + tid;
      float x = xb[p * 3 + 0], y = xb[p * 3 + 1], z = xb[p * 3 + 2];
      float Sn    = fadd(fadd(fmul(x, x), fmul(y, y)), fmul(z, z));
      float inner = fmaf(cz, z, fmaf(cy, y, fmul(cx, x)));
      float d2    = fsub(fadd(Sc, Sn), fmul(2.0f, inner));
      float kk = __fsqrt_rn(fmaxf(d2, 0.0f));
      sd[p] = kk;
      // ballot-combined histogram (R9): one atomic per distinct bucket
      unsigned bucket = __float_as_uint(kk) >> 24;
      unsigned long long rem = __ballot(1);
      while (rem) {
        int leader = (int)__ffsll((unsigned long long)rem) - 1;
        unsigned lb = (unsigned)__shfl((int)bucket, leader);
        unsigned long long mk = __ballot(bucket == lb);
        if (lane == leader) atomicAdd(&myhist[lb], (int)__popcll(mk));
        rem &= ~mk;
      }
    }
    unsigned prefix = 0; int below = 0;
    for (int round = 0; round < 4; round++) {
      const int shift = 24 - 8 * round;
      if (round > 0) {
        for (int i = lane; i < 256; i += 64) myhist[i] = 0;
        __syncthreads();
        for (int j = 0; j < 32; j++) {
          unsigned kb = __float_as_uint(sd[j * 256 + tid]);
          if ((kb >> (shift + 8)) == (prefix >> (shift + 8)))
            atomicAdd(&myhist[(kb >> shift) & 255], 1);
        }
      }
      __syncthreads();
      int h = hist4[tid] + hist4[256 + tid] + hist4[512 + tid] + hist4[768 + tid];
      int v = h;
#pragma unroll
      for (int off = 1; off < 64; off <<= 1) {
        int u = __shfl_up(v, off);
        if (lane >= off) v += u;
      }
      if (lane == 63) wsum[wv] = v;
      __syncthreads();
      int base = below;
      for (int w = 0; w < wv; w++) base += wsum[w];
      int excl = base + v - h;
      if (excl < NK && excl + h >= NK) {    // unique crossing thread
        *sprefix = prefix | ((unsigned)tid << shift);
        *sbelow = excl;
      }
      __syncthreads();
      prefix = *sprefix; below = *sbelow;
    }
    const unsigned K32 = prefix;
    if (tid < 2) cnts[tid] = 0;
    __syncthreads();
    for (int j = 0; j < 32; j++) {
      int p = j * 256 + tid;
      unsigned kb = __float_as_uint(sd[p]);
      bool isA = (kb < K32);
      bool isT = (kb == K32);
      unsigned long long mA = __ballot(isA);
      if (isA) {
        int leader = (int)__ffsll(mA) - 1;
        int basev = 0;
        if (lane == leader) basev = atomicAdd(&cnts[0], (int)__popcll(mA));
        basev = __shfl(basev, leader);
        int q = basev + (int)__popcll(mA & lmask_lt);
        if (q < NK) selA[q] = p;
      }
      unsigned long long mT = __ballot(isT);
      if (isT) {
        int leader = (int)__ffsll(mT) - 1;
        int basev = 0;
        if (lane == leader) basev = atomicAdd(&cnts[1], (int)__popcll(mT));
        basev = __shfl(basev, leader);
        int q = basev + (int)__popcll(mT & lmask_lt);
        if (q < 256) tib[q] = p;
      }
    }
    __syncthreads();
    const int n1 = cnts[0] < NK ? cnts[0] : NK;
    int nt = cnts[1]; if (nt > 256) nt = 256;
    if (tid == 0) {
      int need = NK - n1;
      for (int a = 0; a < need; a++) {       // ties -> lowest indices (top_k stable)
        int bj = -1; int bidx = 0x7fffffff;
        for (int j = 0; j < nt; j++) {
          int p = tib[j];
          if (p >= 0 && p < bidx) { bidx = p; bj = j; }
        }
        if (bj >= 0) { selA[n1 + a] = bidx; tib[bj] = -1; }
        else selA[n1 + a] = selA[0];
      }
      float bk = 1e30f; int bp = 0x7fffffff;  // nearest = (min key, min idx)
      for (int j = 0; j < NK; j++) {
        int p = selA[j]; float kk = sd[p];
        if (kk < bk || (kk == bk && p < bp)) { bk = kk; bp = p; }
      }
      *snear_s = bp;
    }
    __syncthreads();
    // transition: final indices into dead tib region
    int* qsl = tib;
    if (tid < NK) {
      int p = selA[tid];
      qsl[tid] = (sd[p] > 0.25f) ? *snear_s : p;
    }
    __syncthreads();                       // sd/selA dead beyond this point

    // ---- mlp phase (layout inside dead sd region) ----
    float* x1   = smem;             // 32*64
    float* x2   = smem + 2048;      // 32*64
    float* pmax = smem + 4096;      // 8*128
    float* gin  = smem + 5120;      // 32*12

    for (int e = tid; e < 288; e += 256) {
      int k = e / 9, c = e % 9;
      int p = qsl[k];
      float v;
      if (c < 3) {
        float cc = (c == 0) ? cx : (c == 1 ? cy : cz);
        v = fsub(xyz[((size_t)b * NP + p) * 3 + c], cc);
      } else {
        v = points[((size_t)b * NP + p) * 6 + (c - 3)];
      }
      gin[k * 12 + c] = v;
    }
    __syncthreads();
    { // L1
      int o = tid & 63, k0 = (tid >> 6) * 8;
      float wr[9];
#pragma unroll
      for (int c = 0; c < 9; c++) wr[c] = w0[o * 9 + c];
      float bb = b0[o], bm = m0[o], bg = g0[o], bbt = bt0[o];
      float br = 1.0f / __fsqrt_rn(fadd(v0[o], 1e-5f));
#pragma unroll
      for (int j = 0; j < 8; j++) {
        int k = k0 + j;
        const float4* gq = (const float4*)&gin[k * 12];
        float4 q0 = gq[0], q1 = gq[1], q2 = gq[2];
        float acc = 0.f;
        acc = fmaf(wr[0], q0.x, acc); acc = fmaf(wr[1], q0.y, acc);
        acc = fmaf(wr[2], q0.z, acc); acc = fmaf(wr[3], q0.w, acc);
        acc = fmaf(wr[4], q1.x, acc); acc = fmaf(wr[5], q1.y, acc);
        acc = fmaf(wr[6], q1.z, acc); acc = fmaf(wr[7], q1.w, acc);
        acc = fmaf(wr[8], q2.x, acc);
        float y = fadd(acc, bb);
        y = fadd(fmul(fmul(bg, fsub(y, bm)), br), bbt);
        x1[k * 64 + o] = fmaxf(y, 0.f);
      }
    }
    __syncthreads();
    { // L2
      int o0 = (tid & 31) * 2, k0 = (tid >> 5) * 4;
      float acc[2][4];
#pragma unroll
      for (int oo = 0; oo < 2; oo++)
#pragma unroll
        for (int kk = 0; kk < 4; kk++) acc[oo][kk] = 0.f;
#pragma unroll
      for (int c4 = 0; c4 < 16; c4++) {
        float4 xq[4];
#pragma unroll
        for (int kk = 0; kk < 4; kk++) xq[kk] = *(const float4*)&x1[(k0 + kk) * 64 + c4 * 4];
#pragma unroll
        for (int oo = 0; oo < 2; oo++) {
          float4 wq = *(const float4*)&w1[(o0 + oo) * 64 + c4 * 4];
#pragma unroll
          for (int kk = 0; kk < 4; kk++) {
            acc[oo][kk] = fmaf(wq.x, xq[kk].x, acc[oo][kk]);
            acc[oo][kk] = fmaf(wq.y, xq[kk].y, acc[oo][kk]);
            acc[oo][kk] = fmaf(wq.z, xq[kk].z, acc[oo][kk]);
            acc[oo][kk] = fmaf(wq.w, xq[kk].w, acc[oo][kk]);
          }
        }
      }
#pragma unroll
      for (int oo = 0; oo < 2; oo++) {
        int o = o0 + oo;
        float bb = b1[o], bm = m1[o], bg = g1[o], bbt = bt1[o];
        float br = 1.0f / __fsqrt_rn(fadd(v1[o], 1e-5f));
#pragma unroll
        for (int kk = 0; kk < 4; kk++) {
          float y = fadd(acc[oo][kk], bb);
          y = fadd(fmul(fmul(bg, fsub(y, bm)), br), bbt);
          x2[(k0 + kk) * 64 + o] = fmaxf(y, 0.f);
        }
      }
    }
    __syncthreads();
    { // L3 + per-k-group max
      int ch0 = (tid & 31) * 4, k0 = (tid >> 5) * 4, kg = tid >> 5;
      float acc[4][4];
#pragma unroll
      for (int cc = 0; cc < 4; cc++)
#pragma unroll
        for (int kk = 0; kk < 4; kk++) acc[cc][kk] = 0.f;
#pragma unroll
      for (int c4 = 0; c4 < 16; c4++) {
        float4 xq[4];
#pragma unroll
        for (int kk = 0; kk < 4; kk++) xq[kk] = *(const float4*)&x2[(k0 + kk) * 64 + c4 * 4];
#pragma unroll
        for (int cc = 0; cc < 4; cc++) {
          float4 wq = *(const float4*)&w2[(ch0 + cc) * 64 + c4 * 4];
#pragma unroll
          for (int kk = 0; kk < 4; kk++) {
            acc[cc][kk] = fmaf(wq.x, xq[kk].x, acc[cc][kk]);
            acc[cc][kk] = fmaf(wq.y, xq[kk].y, acc[cc][kk]);
            acc[cc][kk] = fmaf(wq.z, xq[kk].z, acc[cc][kk]);
            acc[cc][kk] = fmaf(wq.w, xq[kk].w, acc[cc][kk]);
          }
        }
      }
#pragma unroll
      for (int cc = 0; cc < 4; cc++) {
        int ch = ch0 + cc;
        float bb = b2[ch], bm = m2[ch], bg = g2[ch], bbt = bt2[ch];
        float br = 1.0f / __fsqrt_rn(fadd(v2[ch], 1e-5f));
        float mx = -1e30f;
#pragma unroll
        for (int kk = 0; kk < 4; kk++) {
          float y = fadd(acc[cc][kk], bb);
          y = fadd(fmul(fmul(bg, fsub(y, bm)), br), bbt);
          mx = fmaxf(mx, fmaxf(y, 0.f));
        }
        pmax[kg * 128 + ch] = mx;
      }
    }
    __syncthreads();
    if (tid < 128) {
      float m = pmax[tid];
#pragma unroll
      for (int g = 1; g < 8; g++) m = fmaxf(m, pmax[g * 128 + tid]);
      out_pts[(size_t)cs * 128 + tid] = m;
    }
    __syncthreads();                       // before smem reuse by next item
  }
}

extern "C" void kernel_launch(void* const* d_in, const int* in_sizes, int n_in,
                              void* d_out, int out_size, void* d_ws, size_t ws_size,
                              hipStream_t stream) {
  (void)in_sizes; (void)n_in; (void)out_size; (void)ws_size;
  const float* xyz    = (const float*)d_in[0];
  const float* points = (const float*)d_in[1];
  const float* w0 = (const float*)d_in[2];
  const float* b0 = (const float*)d_in[3];
  const float* g0 = (const float*)d_in[4];
  const float* bt0 = (const float*)d_in[5];
  const float* m0 = (const float*)d_in[6];
  const float* v0 = (const float*)d_in[7];
  const float* w1 = (const float*)d_in[8];
  const float* b1 = (const float*)d_in[9];
  const float* g1 = (const float*)d_in[10];
  const float* bt1 = (const float*)d_in[11];
  const float* m1 = (const float*)d_in[12];
  const float* v1 = (const float*)d_in[13];
  const float* w2 = (const float*)d_in[14];
  const float* b2 = (const float*)d_in[15];
  const float* g2 = (const float*)d_in[16];
  const float* bt2 = (const float*)d_in[17];
  const float* m2 = (const float*)d_in[18];
  const float* v2 = (const float*)d_in[19];

  float* new_xyz = (float*)d_out;                         // 8*2048*3 f32
  float* out_pts = (float*)d_out + (size_t)NB * NS * 3;   // 8*2048*128 f32
  unsigned long long* hs = (unsigned long long*)d_ws;     // 8*2048*3 u64 = 384 KiB

  fused_kernel<<<1024, 256, 0, stream>>>(xyz, points,
                                         w0, b0, g0, bt0, m0, v0,
                                         w1, b1, g1, bt1, m1, v1,
                                         w2, b2, g2, bt2, m2, v2,
                                         new_xyz, out_pts, hs);
}

// Round 18
// 2306.484 us; speedup vs baseline: 1.6365x; 1.3311x over previous
//
#include <hip/hip_runtime.h>
#include <math.h>

// Forbid fma contraction for every expression in this file (np-matching arithmetic).
#pragma clang fp contract(off)

#define NB 8
#define NP 8192
#define NS 2048
#define NK 32
#define NWORK 504            // worker blocks (total grid 520 = 8 fps + 8 spacers + 504)
#define SPACER0 256          // blocks [256,264) exit immediately — vacate fps CUs
#define TAGX 0x5A5A0000u     // tag XOR: defends handshake against ws poison patterns

// Decision-critical f32 ops as raw VALU instructions — cannot be contracted.
__device__ __forceinline__ float fsub(float a, float b) {
  float r; asm("v_sub_f32 %0, %1, %2" : "=v"(r) : "v"(a), "v"(b)); return r;
}
__device__ __forceinline__ float fmul(float a, float b) {
  float r; asm("v_mul_f32 %0, %1, %2" : "=v"(r) : "v"(a), "v"(b)); return r;
}
__device__ __forceinline__ float fadd(float a, float b) {
  float r; asm("v_add_f32 %0, %1, %2" : "=v"(r) : "v"(a), "v"(b)); return r;
}

// ---------------- FUSED persistent producer-consumer kernel ----------------
// R17 post-mortem: doubling workers REGRESSED (+750us) with no occupancy gain
// in effective throughput => system is PRODUCTION-limited and worker polling
// is interference: each waiting tid0 spins on atomicAdd(h,0) — a full RMW
// serializing at the device coherence point, the same fabric fps's publishes
// and winner-coord loads traverse. R18: revert to the best-measured R15
// config (grid 520, spacers, 504 workers) and make the handshake cheap:
//   publish: __hip_atomic_store (coherent store, no RMW round trip)
//   poll:    __hip_atomic_load (coherent load, no write traffic) + s_sleep(4)
// Correctness unchanged: each u64 is self-tagged (payload in the same atom),
// relaxed per-word ordering suffices; agent scope bypasses non-coherent XCD
// L2s exactly as the RMWs did.
//
// fps semantics (R8-verified, bit-identical): unfused f32 distances
// ((dx*dx+dy*dy)+dz*dz, contract(off)); u64 (key<<32 | ~idx) max == (max key,
// lowest index) == np.argmax first-occurrence. Thread t owns points
// j*1024+4t+k; ascending (j,k) => ascending global idx. Register residency
// via volatile LDS loads (planes staged one-at-a-time through smem).
__global__ __launch_bounds__(256, 2) void fused_kernel(
    const float* __restrict__ xyz, const float* __restrict__ points,
    const float* __restrict__ w0, const float* __restrict__ b0, const float* __restrict__ g0,
    const float* __restrict__ bt0, const float* __restrict__ m0, const float* __restrict__ v0,
    const float* __restrict__ w1, const float* __restrict__ b1, const float* __restrict__ g1,
    const float* __restrict__ bt1, const float* __restrict__ m1, const float* __restrict__ v1,
    const float* __restrict__ w2, const float* __restrict__ b2, const float* __restrict__ g2,
    const float* __restrict__ bt2, const float* __restrict__ m2, const float* __restrict__ v2,
    float* __restrict__ new_xyz, float* __restrict__ out_pts,
    unsigned long long* __restrict__ hs) {
  __shared__ __align__(16) float smem[9552];
  __shared__ unsigned long long wbest[2][4];
  __shared__ float cxyz[3];

  const int tid = threadIdx.x;
  const int lane = tid & 63, wv = tid >> 6;
  const int bid = (int)blockIdx.x;

  if (bid >= SPACER0 && bid < SPACER0 + NB) return;   // spacer: vacate fps CU slot

  if (bid < NB) {
    // ================= FPS producer (one block per batch) =================
    __builtin_amdgcn_s_setprio(1);     // protect fps issue from any co-tenant
    const int b = bid;
    const float* xb = xyz + (size_t)b * NP * 3;
    const int tb = tid << 2;
    float* cq = smem + 9000;           // 8-slot centroid queue (24 floats), dead area
    float rx[32], ry[32], rz[32];
    // stage each SoA plane through smem, then volatile-LDS load to registers
    // (volatile = cannot be rematerialized/sunk into the loop; R7-verified)
    for (int i = 0; i < 32; i++) { int p = tid * 32 + i; smem[p] = xb[p * 3 + 0]; }
    __syncthreads();
#pragma unroll
    for (int j = 0; j < 8; j++)
#pragma unroll
      for (int k = 0; k < 4; k++)
        rx[j * 4 + k] = *(volatile const float*)&smem[j * 1024 + tb + k];
    __syncthreads();
    for (int i = 0; i < 32; i++) { int p = tid * 32 + i; smem[p] = xb[p * 3 + 1]; }
    __syncthreads();
#pragma unroll
    for (int j = 0; j < 8; j++)
#pragma unroll
      for (int k = 0; k < 4; k++)
        ry[j * 4 + k] = *(volatile const float*)&smem[j * 1024 + tb + k];
    __syncthreads();
    for (int i = 0; i < 32; i++) { int p = tid * 32 + i; smem[p] = xb[p * 3 + 2]; }
    __syncthreads();
#pragma unroll
    for (int j = 0; j < 8; j++)
#pragma unroll
      for (int k = 0; k < 4; k++)
        rz[j * 4 + k] = *(volatile const float*)&smem[j * 1024 + tb + k];
    __syncthreads();

    float dist[32];
#pragma unroll
    for (int i = 0; i < 32; i++) dist[i] = 1e10f;

    float fx = xb[0], fy = xb[1], fz = xb[2];   // farthest = index 0 at t=0
    for (int t = 0; t < NS; t++) {
      if (tid == 0) {
        // stage centroid t into the LDS queue (cheap ds_write; drains fast)
        const int sl = (t & 7) * 3;
        cq[sl + 0] = fx; cq[sl + 1] = fy; cq[sl + 2] = fz;
        if ((t & 7) == 7) {
          // flush 8 centroids: 24 stores + 24 tagged agent-scope atomic stores
          const int t0 = t - 7;
#pragma unroll
          for (int q = 0; q < 8; q++) {
            const int s = t0 + q;
            float qx = cq[q * 3 + 0], qy = cq[q * 3 + 1], qz = cq[q * 3 + 2];
            float* o = new_xyz + ((size_t)b * NS + s) * 3;
            o[0] = qx; o[1] = qy; o[2] = qz;
            unsigned long long tg =
                (unsigned long long)(((unsigned)(s + 1)) ^ TAGX) << 32;
            unsigned long long* h = hs + ((size_t)b * NS + s) * 3;
            __hip_atomic_store(&h[0], tg | (unsigned long long)__float_as_uint(qx),
                               __ATOMIC_RELAXED, __HIP_MEMORY_SCOPE_AGENT);
            __hip_atomic_store(&h[1], tg | (unsigned long long)__float_as_uint(qy),
                               __ATOMIC_RELAXED, __HIP_MEMORY_SCOPE_AGENT);
            __hip_atomic_store(&h[2], tg | (unsigned long long)__float_as_uint(qz),
                               __ATOMIC_RELAXED, __HIP_MEMORY_SCOPE_AGENT);
          }
        }
      }
      const int par = t & 1;
      float lmax = -1.0f; int li = 0;
#pragma unroll
      for (int i = 0; i < 32; i++) {
        float dx = rx[i] - fx;
        float dy = ry[i] - fy;
        float dz = rz[i] - fz;
        float d = dx * dx + dy * dy + dz * dz;  // contract(off): 3 mul + 2 add
        float nd = fminf(dist[i], d);
        dist[i] = nd;
        bool gt = nd > lmax;
        li = gt ? i : li;
        lmax = gt ? nd : lmax;
      }
      const unsigned gidx = (unsigned)(((li >> 2) << 10) | (tid << 2) | (li & 3));
      // ---- single packed-u64 DPP wave reduce (VALU pipe only) ----
      unsigned long long m = ((unsigned long long)__float_as_uint(lmax) << 32)
                           | (unsigned long long)(~gidx);
#define DPP_MAX64(ctrl) { \
      unsigned _lo = (unsigned)__builtin_amdgcn_update_dpp(0, (int)(unsigned)m, (ctrl), 0xf, 0xf, false); \
      unsigned _hi = (unsigned)__builtin_amdgcn_update_dpp(0, (int)(unsigned)(m >> 32), (ctrl), 0xf, 0xf, false); \
      unsigned long long _o = ((unsigned long long)_hi << 32) | _lo; \
      if (_o > m) m = _o; }
      DPP_MAX64(0x111) DPP_MAX64(0x112) DPP_MAX64(0x114) DPP_MAX64(0x118)
      DPP_MAX64(0x142) DPP_MAX64(0x143)
#undef DPP_MAX64
      if (lane == 63) wbest[par][wv] = m;
      __syncthreads();                          // single barrier per iteration
      unsigned long long mm = wbest[par][0];
#pragma unroll
      for (int w = 1; w < 4; w++) { unsigned long long c = wbest[par][w]; if (c > mm) mm = c; }
      int bp = (int)(~(unsigned)(mm & 0xFFFFFFFFull));
      // winner coords from global (L2-hot; identical bits to the staged copy)
      fx = xb[bp * 3 + 0]; fy = xb[bp * 3 + 1]; fz = xb[bp * 3 + 2];
      // parity double-buffer: next iteration writes wbest[1-par] — no WAR race
    }
    return;
  }

  // ================= ball+mlp worker (persistent, s-major items) =================
  const int wid = (bid < SPACER0) ? (bid - NB) : (bid - NB - NB);  // 0..503
  // ball-phase layout
  float* sd         = smem;                      // 8192 keys
  int* hist4        = (int*)(smem + 8192);       // 4 waves x 256 buckets
  int* cnts         = (int*)(smem + 9216);       // 2
  unsigned* sprefix = (unsigned*)(smem + 9218);
  int* sbelow       = (int*)(smem + 9219);
  int* snear_s      = (int*)(smem + 9220);
  int* wsum         = (int*)(smem + 9224);       // 4
  int* selA         = (int*)(smem + 9232);       // 32
  int* tib          = (int*)(smem + 9264);       // 256 (reused as qsl)
  int* myhist = hist4 + wv * 256;
  const unsigned long long lmask_lt = (lane == 0) ? 0ull : (~0ull >> (64 - lane));

  for (int jit = wid; jit < NB * NS; jit += NWORK) {
    const int s = jit >> 3, b = jit & 7;
    const int cs = b * NS + s;
    const float* xb = xyz + (size_t)b * NP * 3;
    // ---- wait for centroid (b,s): poll tagged words with coherent LOADS ----
    if (tid == 0) {
      const unsigned want = ((unsigned)(s + 1)) ^ TAGX;
      unsigned long long* h = hs + ((size_t)b * NS + s) * 3;
      unsigned long long v0, v1, v2;
      for (;;) { v0 = __hip_atomic_load(&h[0], __ATOMIC_RELAXED, __HIP_MEMORY_SCOPE_AGENT);
                 if ((unsigned)(v0 >> 32) == want) break; __builtin_amdgcn_s_sleep(4); }
      for (;;) { v1 = __hip_atomic_load(&h[1], __ATOMIC_RELAXED, __HIP_MEMORY_SCOPE_AGENT);
                 if ((unsigned)(v1 >> 32) == want) break; __builtin_amdgcn_s_sleep(4); }
      for (;;) { v2 = __hip_atomic_load(&h[2], __ATOMIC_RELAXED, __HIP_MEMORY_SCOPE_AGENT);
                 if ((unsigned)(v2 >> 32) == want) break; __builtin_amdgcn_s_sleep(4); }
      cxyz[0] = __uint_as_float((unsigned)v0);
      cxyz[1] = __uint_as_float((unsigned)v1);
      cxyz[2] = __uint_as_float((unsigned)v2);
    }
    __syncthreads();
    const float cx = cxyz[0], cy = cxyz[1], cz = cxyz[2];
    const float Sc = fadd(fadd(fmul(cx, cx), fmul(cy, cy)), fmul(cz, cz));
    for (int i = lane; i < 256; i += 64) myhist[i] = 0;
    for (int j = 0; j < 32; j++) {
      int p = j * 256 + tid;
      float x = xb[p * 3 + 0], y = xb[p * 3 + 1], z = xb[p * 3 + 2];
      float Sn    = fadd(fadd(fmul(x, x), fmul(y, y)), fmul(z, z));
      float inner = fmaf(cz, z, fmaf(cy, y, fmul(cx, x)));
      float d2    = fsub(fadd(Sc, Sn), fmul(2.0f, inner));
      float kk = __fsqrt_rn(fmaxf(d2, 0.0f));
      sd[p] = kk;
      // ballot-combined histogram (R9): one atomic per distinct bucket
      unsigned bucket = __float_as_uint(kk) >> 24;
      unsigned long long rem = __ballot(1);
      while (rem) {
        int leader = (int)__ffsll((unsigned long long)rem) - 1;
        unsigned lb = (unsigned)__shfl((int)bucket, leader);
        unsigned long long mk = __ballot(bucket == lb);
        if (lane == leader) atomicAdd(&myhist[lb], (int)__popcll(mk));
        rem &= ~mk;
      }
    }
    unsigned prefix = 0; int below = 0;
    for (int round = 0; round < 4; round++) {
      const int shift = 24 - 8 * round;
      if (round > 0) {
        for (int i = lane; i < 256; i += 64) myhist[i] = 0;
        __syncthreads();
        for (int j = 0; j < 32; j++) {
          unsigned kb = __float_as_uint(sd[j * 256 + tid]);
          if ((kb >> (shift + 8)) == (prefix >> (shift + 8)))
            atomicAdd(&myhist[(kb >> shift) & 255], 1);
        }
      }
      __syncthreads();
      int h = hist4[tid] + hist4[256 + tid] + hist4[512 + tid] + hist4[768 + tid];
      int v = h;
#pragma unroll
      for (int off = 1; off < 64; off <<= 1) {
        int u = __shfl_up(v, off);
        if (lane >= off) v += u;
      }
      if (lane == 63) wsum[wv] = v;
      __syncthreads();
      int base = below;
      for (int w = 0; w < wv; w++) base += wsum[w];
      int excl = base + v - h;
      if (excl < NK && excl + h >= NK) {    // unique crossing thread
        *sprefix = prefix | ((unsigned)tid << shift);
        *sbelow = excl;
      }
      __syncthreads();
      prefix = *sprefix; below = *sbelow;
    }
    const unsigned K32 = prefix;
    if (tid < 2) cnts[tid] = 0;
    __syncthreads();
    for (int j = 0; j < 32; j++) {
      int p = j * 256 + tid;
      unsigned kb = __float_as_uint(sd[p]);
      bool isA = (kb < K32);
      bool isT = (kb == K32);
      unsigned long long mA = __ballot(isA);
      if (isA) {
        int leader = (int)__ffsll(mA) - 1;
        int basev = 0;
        if (lane == leader) basev = atomicAdd(&cnts[0], (int)__popcll(mA));
        basev = __shfl(basev, leader);
        int q = basev + (int)__popcll(mA & lmask_lt);
        if (q < NK) selA[q] = p;
      }
      unsigned long long mT = __ballot(isT);
      if (isT) {
        int leader = (int)__ffsll(mT) - 1;
        int basev = 0;
        if (lane == leader) basev = atomicAdd(&cnts[1], (int)__popcll(mT));
        basev = __shfl(basev, leader);
        int q = basev + (int)__popcll(mT & lmask_lt);
        if (q < 256) tib[q] = p;
      }
    }
    __syncthreads();
    const int n1 = cnts[0] < NK ? cnts[0] : NK;
    int nt = cnts[1]; if (nt > 256) nt = 256;
    if (tid == 0) {
      int need = NK - n1;
      for (int a = 0; a < need; a++) {       // ties -> lowest indices (top_k stable)
        int bj = -1; int bidx = 0x7fffffff;
        for (int j = 0; j < nt; j++) {
          int p = tib[j];
          if (p >= 0 && p < bidx) { bidx = p; bj = j; }
        }
        if (bj >= 0) { selA[n1 + a] = bidx; tib[bj] = -1; }
        else selA[n1 + a] = selA[0];
      }
      float bk = 1e30f; int bp = 0x7fffffff;  // nearest = (min key, min idx)
      for (int j = 0; j < NK; j++) {
        int p = selA[j]; float kk = sd[p];
        if (kk < bk || (kk == bk && p < bp)) { bk = kk; bp = p; }
      }
      *snear_s = bp;
    }
    __syncthreads();
    // transition: final indices into dead tib region
    int* qsl = tib;
    if (tid < NK) {
      int p = selA[tid];
      qsl[tid] = (sd[p] > 0.25f) ? *snear_s : p;
    }
    __syncthreads();                       // sd/selA dead beyond this point

    // ---- mlp phase (layout inside dead sd region) ----
    float* x1   = smem;             // 32*64
    float* x2   = smem + 2048;      // 32*64
    float* pmax = smem + 4096;      // 8*128
    float* gin  = smem + 5120;      // 32*12

    for (int e = tid; e < 288; e += 256) {
      int k = e / 9, c = e % 9;
      int p = qsl[k];
      float v;
      if (c < 3) {
        float cc = (c == 0) ? cx : (c == 1 ? cy : cz);
        v = fsub(xyz[((size_t)b * NP + p) * 3 + c], cc);
      } else {
        v = points[((size_t)b * NP + p) * 6 + (c - 3)];
      }
      gin[k * 12 + c] = v;
    }
    __syncthreads();
    { // L1
      int o = tid & 63, k0 = (tid >> 6) * 8;
      float wr[9];
#pragma unroll
      for (int c = 0; c < 9; c++) wr[c] = w0[o * 9 + c];
      float bb = b0[o], bm = m0[o], bg = g0[o], bbt = bt0[o];
      float br = 1.0f / __fsqrt_rn(fadd(v0[o], 1e-5f));
#pragma unroll
      for (int j = 0; j < 8; j++) {
        int k = k0 + j;
        const float4* gq = (const float4*)&gin[k * 12];
        float4 q0 = gq[0], q1 = gq[1], q2 = gq[2];
        float acc = 0.f;
        acc = fmaf(wr[0], q0.x, acc); acc = fmaf(wr[1], q0.y, acc);
        acc = fmaf(wr[2], q0.z, acc); acc = fmaf(wr[3], q0.w, acc);
        acc = fmaf(wr[4], q1.x, acc); acc = fmaf(wr[5], q1.y, acc);
        acc = fmaf(wr[6], q1.z, acc); acc = fmaf(wr[7], q1.w, acc);
        acc = fmaf(wr[8], q2.x, acc);
        float y = fadd(acc, bb);
        y = fadd(fmul(fmul(bg, fsub(y, bm)), br), bbt);
        x1[k * 64 + o] = fmaxf(y, 0.f);
      }
    }
    __syncthreads();
    { // L2
      int o0 = (tid & 31) * 2, k0 = (tid >> 5) * 4;
      float acc[2][4];
#pragma unroll
      for (int oo = 0; oo < 2; oo++)
#pragma unroll
        for (int kk = 0; kk < 4; kk++) acc[oo][kk] = 0.f;
#pragma unroll
      for (int c4 = 0; c4 < 16; c4++) {
        float4 xq[4];
#pragma unroll
        for (int kk = 0; kk < 4; kk++) xq[kk] = *(const float4*)&x1[(k0 + kk) * 64 + c4 * 4];
#pragma unroll
        for (int oo = 0; oo < 2; oo++) {
          float4 wq = *(const float4*)&w1[(o0 + oo) * 64 + c4 * 4];
#pragma unroll
          for (int kk = 0; kk < 4; kk++) {
            acc[oo][kk] = fmaf(wq.x, xq[kk].x, acc[oo][kk]);
            acc[oo][kk] = fmaf(wq.y, xq[kk].y, acc[oo][kk]);
            acc[oo][kk] = fmaf(wq.z, xq[kk].z, acc[oo][kk]);
            acc[oo][kk] = fmaf(wq.w, xq[kk].w, acc[oo][kk]);
          }
        }
      }
#pragma unroll
      for (int oo = 0; oo < 2; oo++) {
        int o = o0 + oo;
        float bb = b1[o], bm = m1[o], bg = g1[o], bbt = bt1[o];
        float br = 1.0f / __fsqrt_rn(fadd(v1[o], 1e-5f));
#pragma unroll
        for (int kk = 0; kk < 4; kk++) {
          float y = fadd(acc[oo][kk], bb);
          y = fadd(fmul(fmul(bg, fsub(y, bm)), br), bbt);
          x2[(k0 + kk) * 64 + o] = fmaxf(y, 0.f);
        }
      }
    }
    __syncthreads();
    { // L3 + per-k-group max
      int ch0 = (tid & 31) * 4, k0 = (tid >> 5) * 4, kg = tid >> 5;
      float acc[4][4];
#pragma unroll
      for (int cc = 0; cc < 4; cc++)
#pragma unroll
        for (int kk = 0; kk < 4; kk++) acc[cc][kk] = 0.f;
#pragma unroll
      for (int c4 = 0; c4 < 16; c4++) {
        float4 xq[4];
#pragma unroll
        for (int kk = 0; kk < 4; kk++) xq[kk] = *(const float4*)&x2[(k0 + kk) * 64 + c4 * 4];
#pragma unroll
        for (int cc = 0; cc < 4; cc++) {
          float4 wq = *(const float4*)&w2[(ch0 + cc) * 64 + c4 * 4];
#pragma unroll
          for (int kk = 0; kk < 4; kk++) {
            acc[cc][kk] = fmaf(wq.x, xq[kk].x, acc[cc][kk]);
            acc[cc][kk] = fmaf(wq.y, xq[kk].y, acc[cc][kk]);
            acc[cc][kk] = fmaf(wq.z, xq[kk].z, acc[cc][kk]);
            acc[cc][kk] = fmaf(wq.w, xq[kk].w, acc[cc][kk]);
          }
        }
      }
#pragma unroll
      for (int cc = 0; cc < 4; cc++) {
        int ch = ch0 + cc;
        float bb = b2[ch], bm = m2[ch], bg = g2[ch], bbt = bt2[ch];
        float br = 1.0f / __fsqrt_rn(fadd(v2[ch], 1e-5f));
        float mx = -1e30f;
#pragma unroll
        for (int kk = 0; kk < 4; kk++) {
          float y = fadd(acc[cc][kk], bb);
          y = fadd(fmul(fmul(bg, fsub(y, bm)), br), bbt);
          mx = fmaxf(mx, fmaxf(y, 0.f));
        }
        pmax[kg * 128 + ch] = mx;
      }
    }
    __syncthreads();
    if (tid < 128) {
      float m = pmax[tid];
#pragma unroll
      for (int g = 1; g < 8; g++) m = fmaxf(m, pmax[g * 128 + tid]);
      out_pts[(size_t)cs * 128 + tid] = m;
    }
    __syncthreads();                       // before smem reuse by next item
  }
}

extern "C" void kernel_launch(void* const* d_in, const int* in_sizes, int n_in,
                              void* d_out, int out_size, void* d_ws, size_t ws_size,
                              hipStream_t stream) {
  (void)in_sizes; (void)n_in; (void)out_size; (void)ws_size;
  const float* xyz    = (const float*)d_in[0];
  const float* points = (const float*)d_in[1];
  const float* w0 = (const float*)d_in[2];
  const float* b0 = (const float*)d_in[3];
  const float* g0 = (const float*)d_in[4];
  const float* bt0 = (const float*)d_in[5];
  const float* m0 = (const float*)d_in[6];
  const float* v0 = (const float*)d_in[7];
  const float* w1 = (const float*)d_in[8];
  const float* b1 = (const float*)d_in[9];
  const float* g1 = (const float*)d_in[10];
  const float* bt1 = (const float*)d_in[11];
  const float* m1 = (const float*)d_in[12];
  const float* v1 = (const float*)d_in[13];
  const float* w2 = (const float*)d_in[14];
  const float* b2 = (const float*)d_in[15];
  const float* g2 = (const float*)d_in[16];
  const float* bt2 = (const float*)d_in[17];
  const float* m2 = (const float*)d_in[18];
  const float* v2 = (const float*)d_in[19];

  float* new_xyz = (float*)d_out;                         // 8*2048*3 f32
  float* out_pts = (float*)d_out + (size_t)NB * NS * 3;   // 8*2048*128 f32
  unsigned long long* hs = (unsigned long long*)d_ws;     // 8*2048*3 u64 = 384 KiB

  fused_kernel<<<SPACER0 + NB + (NWORK - (SPACER0 - NB)), 256, 0, stream>>>(
                                               xyz, points,
                                               w0, b0, g0, bt0, m0, v0,
                                               w1, b1, g1, bt1, m1, v1,
                                               w2, b2, g2, bt2, m2, v2,
                                               new_xyz, out_pts, hs);
}